// Round 4
// baseline (1350.866 us; speedup 1.0000x reference)
//
#include <hip/hip_runtime.h>

typedef __attribute__((ext_vector_type(8))) short bf16x8;
typedef __attribute__((ext_vector_type(4))) float f32x4;

#define NB 2048
#define NC 64
#define NH 256
#define ND 512
#define NG 768   // 3*NH
#define WIH_LD 576  // NC + ND

__device__ __forceinline__ unsigned short f2b(float f) {
  union { float f; unsigned u; } v; v.f = f;
  unsigned r = v.u + 0x7FFFu + ((v.u >> 16) & 1u);
  return (unsigned short)(r >> 16);
}
__device__ __forceinline__ float b2f(unsigned short h) {
  union { unsigned u; float f; } v; v.u = ((unsigned)h) << 16;
  return v.f;
}
__device__ __forceinline__ float fastsig(float x) {
  return __builtin_amdgcn_rcpf(1.0f + __expf(-x));
}
__device__ __forceinline__ float fasttanh(float x) {
  return 1.0f - 2.0f * __builtin_amdgcn_rcpf(__expf(2.0f * x) + 1.0f);
}

// ---------------- prep: bf16 conversions, packed W_hh, transposes ----------------
__global__ void k_prep(const float* __restrict__ X, const float* __restrict__ Y,
                       const float* __restrict__ W_ih, const float* __restrict__ W_hh,
                       unsigned short* __restrict__ Xb, unsigned short* __restrict__ Wxb,
                       unsigned short* __restrict__ Wp8, float* __restrict__ WpT,
                       float* __restrict__ YT)
{
  const int stride = gridDim.x * blockDim.x;
  const int i0 = blockIdx.x * blockDim.x + threadIdx.x;
  for (int i = i0; i < NB * ND; i += stride) Xb[i] = f2b(X[i]);
  for (int i = i0; i < NG * ND; i += stride) {
    int r = i >> 9, k = i & (ND - 1);
    Wxb[i] = f2b(W_ih[r * WIH_LD + NC + k]);
  }
  // W_hh packed to MFMA fragment order: i = (g<<16)+(cc<<12)+(kk<<9)+(lane<<3)+e
  for (int i = i0; i < NG * NH; i += stride) {
    int e = i & 7, ln = (i >> 3) & 63, kk = (i >> 9) & 7, cc = (i >> 12) & 15, g = i >> 16;
    int col = cc * 16 + (ln & 15), k = kk * 32 + (ln >> 4) * 8 + e;
    Wp8[i] = f2b(W_hh[(g * NH + col) * NH + k]);
  }
  for (int i = i0; i < NC * NG; i += stride) {
    int p = i / NG, g = i - p * NG;
    WpT[i] = W_ih[g * WIH_LD + p];
  }
  for (int i = i0; i < NC * NB; i += stride) {
    int cbl = i >> 11, b = i & (NB - 1);
    YT[i] = Y[b * NC + cbl];
  }
}

// ---------------- gxT[col][row] = (Xb @ Wxb^T + b_ih)^T  (fp32) ----------------
__global__ __launch_bounds__(256) void k_gx(const unsigned short* __restrict__ Xb,
                                            const unsigned short* __restrict__ Wxb,
                                            const float* __restrict__ b_ih,
                                            float* __restrict__ gxT)
{
  const int row0 = blockIdx.x * 64;
  const int col0 = blockIdx.y * 64;
  const int tid = threadIdx.x;
  const int w = tid >> 6, lane = tid & 63;
  const int l15 = lane & 15, lg = lane >> 4;
  const int col = col0 + w * 16 + l15;
  f32x4 acc[4] = {};
  for (int kk = 0; kk < 16; ++kk) {
    const int k0 = kk * 32 + lg * 8;
    bf16x8 b = *reinterpret_cast<const bf16x8*>(&Wxb[col * ND + k0]);
#pragma unroll
    for (int m = 0; m < 4; ++m) {
      const int row = row0 + m * 16 + l15;
      bf16x8 a = *reinterpret_cast<const bf16x8*>(&Xb[row * ND + k0]);
      acc[m] = __builtin_amdgcn_mfma_f32_16x16x32_bf16(a, b, acc[m], 0, 0, 0);
    }
  }
  const float bi = b_ih[col];
#pragma unroll
  for (int m = 0; m < 4; ++m) {
    f32x4 o = acc[m];
    o[0] += bi; o[1] += bi; o[2] += bi; o[3] += bi;
    *reinterpret_cast<f32x4*>(&gxT[col * NB + row0 + m * 16 + lg * 4]) = o;
  }
}

// ---------------- fused GRU chain + logits ----------------
// grid: (32 batch-tiles of 64 rows, 64 classes), 256 threads (4 waves)
// LDS: single 32 KB h buffer (bf16, XOR-swizzled). h_new carried in registers
// across the read->write barrier; reused as h_old next step.
__global__ __launch_bounds__(256, 3) void k_chain(const float* __restrict__ YT,
                                                  const float* __restrict__ gxT,
                                                  const unsigned short* __restrict__ Wp8,
                                                  const float* __restrict__ WpT,
                                                  const float* __restrict__ b_hh,
                                                  const float* __restrict__ W_out,
                                                  const float* __restrict__ b_out,
                                                  float* __restrict__ out)
{
  __shared__ unsigned short hs[64 * NH];   // 32768 B

  const int c = blockIdx.y;
  const int row0 = blockIdx.x * 64;
  const int tid = threadIdx.x;
  const int w = tid >> 6, lane = tid & 63;
  const int l15 = lane & 15, lg = lane >> 4;
  const int nsteps = (c == 0) ? 1 : (c < 3 ? c : 3);
  const float myv = (c == 0) ? 0.0f : 1.0f;
  const int pbase = (c == 0) ? 0 : (c - nsteps);

  unsigned hreg[4][4][2];   // packed bf16 pairs: [group][m][qpair]

  for (int t = 0; t < nsteps; ++t) {
    const int p = pbase + t;
    if (t > 0) __syncthreads();   // prev step's h writes visible

    // yv per 4-row group (folded My mask), hoisted per step
    f32x4 yv[4];
#pragma unroll
    for (int m = 0; m < 4; ++m) {
      f32x4 yl = *reinterpret_cast<const f32x4*>(&YT[p * NB + row0 + m * 16 + lg * 4]);
      yv[m][0] = myv * yl[0]; yv[m][1] = myv * yl[1];
      yv[m][2] = myv * yl[2]; yv[m][3] = myv * yl[3];
    }

#pragma unroll
    for (int g = 0; g < 4; ++g) {
      const int jj = w * 64 + g * 16 + l15;
      const float wpr = WpT[p * NG + jj];
      const float wpz = WpT[p * NG + NH + jj];
      const float wpn = WpT[p * NG + 2 * NH + jj];
      const float bhr = b_hh[jj], bhz = b_hh[NH + jj], bhn = b_hh[2 * NH + jj];

      f32x4 ar[4], az[4], an[4], gin[4];
#pragma unroll
      for (int m = 0; m < 4; ++m) {
        const int r0g = row0 + m * 16 + lg * 4;
        f32x4 gr = *reinterpret_cast<const f32x4*>(&gxT[jj * NB + r0g]);
        f32x4 gz = *reinterpret_cast<const f32x4*>(&gxT[(NH + jj) * NB + r0g]);
        f32x4 gn = *reinterpret_cast<const f32x4*>(&gxT[(2 * NH + jj) * NB + r0g]);
#pragma unroll
        for (int q = 0; q < 4; ++q) {
          ar[m][q] = gr[q] + yv[m][q] * wpr + bhr;
          az[m][q] = gz[q] + yv[m][q] * wpz + bhz;
          gin[m][q] = gn[q] + yv[m][q] * wpn;
          an[m][q] = bhn;
        }
      }

      if (t > 0) {
        const int cc = w * 4 + g;
#pragma unroll
        for (int kk = 0; kk < 8; ++kk) {
          const int k0 = kk * 32 + lg * 8;
          bf16x8 a[4];
#pragma unroll
          for (int m = 0; m < 4; ++m) {
            const int row = m * 16 + l15;
            a[m] = *reinterpret_cast<const bf16x8*>(&hs[row * NH + (k0 ^ ((row & 7) << 3))]);
          }
          const int boff = (cc << 12) + (kk << 9) + lane * 8;
          const bf16x8 br = *reinterpret_cast<const bf16x8*>(&Wp8[boff]);
          const bf16x8 bz = *reinterpret_cast<const bf16x8*>(&Wp8[65536 + boff]);
          const bf16x8 bn = *reinterpret_cast<const bf16x8*>(&Wp8[131072 + boff]);
#pragma unroll
          for (int m = 0; m < 4; ++m) {
            ar[m] = __builtin_amdgcn_mfma_f32_16x16x32_bf16(a[m], br, ar[m], 0, 0, 0);
            az[m] = __builtin_amdgcn_mfma_f32_16x16x32_bf16(a[m], bz, az[m], 0, 0, 0);
            an[m] = __builtin_amdgcn_mfma_f32_16x16x32_bf16(a[m], bn, an[m], 0, 0, 0);
          }
        }
      }

      // epilogue: pure register math; C/D layout col=lane&15, row=(lane>>4)*4+reg
#pragma unroll
      for (int m = 0; m < 4; ++m) {
#pragma unroll
        for (int i = 0; i < 2; ++i) {
          unsigned pack = 0;
#pragma unroll
          for (int hq = 0; hq < 2; ++hq) {
            const int q = i * 2 + hq;
            float r = fastsig(ar[m][q]);
            float z = fastsig(az[m][q]);
            float n = fasttanh(gin[m][q] + r * an[m][q]);
            float hold = 0.0f;
            if (t > 0) {
              const unsigned hp = hreg[g][m][i];
              hold = b2f((unsigned short)(hq ? (hp >> 16) : (hp & 0xffffu)));
            }
            float hnew = n + z * (hold - n);
            pack |= ((unsigned)f2b(hnew)) << (hq * 16);
          }
          hreg[g][m][i] = pack;
        }
      }
    }

    // write phase: all reads of h_old done
    __syncthreads();
#pragma unroll
    for (int g = 0; g < 4; ++g) {
      const int jj = w * 64 + g * 16 + l15;
#pragma unroll
      for (int m = 0; m < 4; ++m)
#pragma unroll
        for (int i = 0; i < 2; ++i) {
          const unsigned hp = hreg[g][m][i];
          const int r0 = m * 16 + lg * 4 + i * 2;
          hs[r0 * NH + (jj ^ ((r0 & 7) << 3))] = (unsigned short)(hp & 0xffffu);
          hs[(r0 + 1) * NH + (jj ^ (((r0 + 1) & 7) << 3))] = (unsigned short)(hp >> 16);
        }
    }
  }

  // ---- logits: out[b][c] = h . W_out[c] + b_out[c] ----
  __syncthreads();
  {
    const int row = tid >> 2, part = tid & 3;  // 4 threads per batch row, 64 js each
    float s = 0.0f;
#pragma unroll
    for (int v = 0; v < 8; ++v) {
      const int e0 = part * 64 + v * 8;
      const bf16x8 hv = *reinterpret_cast<const bf16x8*>(&hs[row * NH + (e0 ^ ((row & 7) << 3))]);
      const f32x4 w0 = *reinterpret_cast<const f32x4*>(&W_out[c * NH + e0]);
      const f32x4 w1 = *reinterpret_cast<const f32x4*>(&W_out[c * NH + e0 + 4]);
      s += b2f((unsigned short)hv[0]) * w0[0] + b2f((unsigned short)hv[1]) * w0[1]
         + b2f((unsigned short)hv[2]) * w0[2] + b2f((unsigned short)hv[3]) * w0[3]
         + b2f((unsigned short)hv[4]) * w1[0] + b2f((unsigned short)hv[5]) * w1[1]
         + b2f((unsigned short)hv[6]) * w1[2] + b2f((unsigned short)hv[7]) * w1[3];
    }
    s += __shfl_xor(s, 1);
    s += __shfl_xor(s, 2);
    if (part == 0) out[(row0 + row) * NC + c] = s + b_out[c];
  }
}

extern "C" void kernel_launch(void* const* d_in, const int* in_sizes, int n_in,
                              void* d_out, int out_size, void* d_ws, size_t ws_size,
                              hipStream_t stream)
{
  const float* X     = (const float*)d_in[0];
  const float* Y     = (const float*)d_in[1];
  const float* W_ih  = (const float*)d_in[2];
  const float* W_hh  = (const float*)d_in[3];
  const float* b_ih  = (const float*)d_in[4];
  const float* b_hh  = (const float*)d_in[5];
  const float* W_out = (const float*)d_in[6];
  const float* b_out = (const float*)d_in[7];
  float* out = (float*)d_out;

  char* ws = (char*)d_ws;
  float*          gxT = (float*)ws;                          // 6291456 B
  unsigned short* Xb  = (unsigned short*)(ws + 6291456);     // 2097152 B
  unsigned short* Wxb = (unsigned short*)(ws + 8388608);     //  786432 B
  unsigned short* Wp8 = (unsigned short*)(ws + 9175040);     //  393216 B
  float*          WpT = (float*)(ws + 9568256);              //  196608 B
  float*          YT  = (float*)(ws + 9764864);              //  524288 B

  k_prep<<<dim3(1024), dim3(256), 0, stream>>>(X, Y, W_ih, W_hh, Xb, Wxb, Wp8, WpT, YT);
  k_gx<<<dim3(32, 12), dim3(256), 0, stream>>>(Xb, Wxb, b_ih, gxT);
  k_chain<<<dim3(32, 64), dim3(256), 0, stream>>>(YT, gxT, Wp8, WpT, b_hh, W_out, b_out, out);
}

// Round 5
// 474.266 us; speedup vs baseline: 2.8483x; 2.8483x over previous
//
#include <hip/hip_runtime.h>

typedef __attribute__((ext_vector_type(8))) short bf16x8;
typedef __attribute__((ext_vector_type(4))) float f32x4;

#define NB 2048
#define NC 64
#define NH 256
#define ND 512
#define NG 768   // 3*NH
#define WIH_LD 576  // NC + ND

__device__ __forceinline__ unsigned short f2b(float f) {
  union { float f; unsigned u; } v; v.f = f;
  unsigned r = v.u + 0x7FFFu + ((v.u >> 16) & 1u);
  return (unsigned short)(r >> 16);
}
__device__ __forceinline__ float b2f(unsigned short h) {
  union { unsigned u; float f; } v; v.u = ((unsigned)h) << 16;
  return v.f;
}
__device__ __forceinline__ float fastsig(float x) {
  return __builtin_amdgcn_rcpf(1.0f + __expf(-x));
}
__device__ __forceinline__ float fasttanh(float x) {
  return 1.0f - 2.0f * __builtin_amdgcn_rcpf(__expf(2.0f * x) + 1.0f);
}

// ---------------- prep: bf16 conversions, packed W_hh, transposes ----------------
__global__ void k_prep(const float* __restrict__ X, const float* __restrict__ Y,
                       const float* __restrict__ W_ih, const float* __restrict__ W_hh,
                       unsigned short* __restrict__ Xb, unsigned short* __restrict__ Wxb,
                       unsigned short* __restrict__ Wp8, float* __restrict__ WpT,
                       float* __restrict__ YT)
{
  const int stride = gridDim.x * blockDim.x;
  const int i0 = blockIdx.x * blockDim.x + threadIdx.x;
  for (int i = i0; i < NB * ND; i += stride) Xb[i] = f2b(X[i]);
  for (int i = i0; i < NG * ND; i += stride) {
    int r = i >> 9, k = i & (ND - 1);
    Wxb[i] = f2b(W_ih[r * WIH_LD + NC + k]);
  }
  // W_hh packed to MFMA fragment order: i = (g<<16)+(cc<<12)+(kk<<9)+(lane<<3)+e
  for (int i = i0; i < NG * NH; i += stride) {
    int e = i & 7, ln = (i >> 3) & 63, kk = (i >> 9) & 7, cc = (i >> 12) & 15, g = i >> 16;
    int col = cc * 16 + (ln & 15), k = kk * 32 + (ln >> 4) * 8 + e;
    Wp8[i] = f2b(W_hh[(g * NH + col) * NH + k]);
  }
  for (int i = i0; i < NC * NG; i += stride) {
    int p = i / NG, g = i - p * NG;
    WpT[i] = W_ih[g * WIH_LD + p];
  }
  for (int i = i0; i < NC * NB; i += stride) {
    int cbl = i >> 11, b = i & (NB - 1);
    YT[i] = Y[b * NC + cbl];
  }
}

// ---------------- gxT[col][row] = (Xb @ Wxb^T + b_ih)^T  (fp32) ----------------
__global__ __launch_bounds__(256) void k_gx(const unsigned short* __restrict__ Xb,
                                            const unsigned short* __restrict__ Wxb,
                                            const float* __restrict__ b_ih,
                                            float* __restrict__ gxT)
{
  const int row0 = blockIdx.x * 64;
  const int col0 = blockIdx.y * 64;
  const int tid = threadIdx.x;
  const int w = tid >> 6, lane = tid & 63;
  const int l15 = lane & 15, lg = lane >> 4;
  const int col = col0 + w * 16 + l15;
  f32x4 acc[4] = {};
  for (int kk = 0; kk < 16; ++kk) {
    const int k0 = kk * 32 + lg * 8;
    bf16x8 b = *reinterpret_cast<const bf16x8*>(&Wxb[col * ND + k0]);
#pragma unroll
    for (int m = 0; m < 4; ++m) {
      const int row = row0 + m * 16 + l15;
      bf16x8 a = *reinterpret_cast<const bf16x8*>(&Xb[row * ND + k0]);
      acc[m] = __builtin_amdgcn_mfma_f32_16x16x32_bf16(a, b, acc[m], 0, 0, 0);
    }
  }
  const float bi = b_ih[col];
#pragma unroll
  for (int m = 0; m < 4; ++m) {
    f32x4 o = acc[m];
    o[0] += bi; o[1] += bi; o[2] += bi; o[3] += bi;
    *reinterpret_cast<f32x4*>(&gxT[col * NB + row0 + m * 16 + lg * 4]) = o;
  }
}

// ---------------- fused GRU chain + logits ----------------
// grid: (64 batch-tiles of 32 rows, 64 classes), 256 threads (4 waves)
// LDS: 32 KB h double-buffer (bf16, XOR-swizzled); h_old carried in registers.
// One barrier per step.
__global__ __launch_bounds__(256) void k_chain(const float* __restrict__ YT,
                                               const float* __restrict__ gxT,
                                               const unsigned short* __restrict__ Wp8,
                                               const float* __restrict__ WpT,
                                               const float* __restrict__ b_hh,
                                               const float* __restrict__ W_out,
                                               const float* __restrict__ b_out,
                                               float* __restrict__ out)
{
  __shared__ unsigned short hb[2][32 * NH];   // 2 x 16384 B

  const int c = blockIdx.y;
  const int row0 = blockIdx.x * 32;
  const int tid = threadIdx.x;
  const int w = tid >> 6, lane = tid & 63;
  const int l15 = lane & 15, lg = lane >> 4;
  const int nsteps = (c == 0) ? 1 : (c < 3 ? c : 3);
  const float myv = (c == 0) ? 0.0f : 1.0f;
  const int pbase = (c == 0) ? 0 : (c - nsteps);

  // b_hh per-lane registers (constant across steps)
  float bhr[4], bhz[4], bhn[4];
#pragma unroll
  for (int jc = 0; jc < 4; ++jc) {
    const int jj = jc * 64 + w * 16 + l15;
    bhr[jc] = b_hh[jj]; bhz[jc] = b_hh[NH + jj]; bhn[jc] = b_hh[2 * NH + jj];
  }

  unsigned hreg[4][2][2];   // packed bf16 pairs: [jc][m][qpair]

  for (int t = 0; t < nsteps; ++t) {
    const int p = pbase + t;
    const unsigned short* hr = hb[t & 1];
    unsigned short* hw = hb[(t + 1) & 1];
    if (t > 0) __syncthreads();   // prev step's writes visible before A-frag reads

    f32x4 yv[2];
#pragma unroll
    for (int m = 0; m < 2; ++m) {
      f32x4 yl = *reinterpret_cast<const f32x4*>(&YT[p * NB + row0 + m * 16 + lg * 4]);
      yv[m][0] = myv * yl[0]; yv[m][1] = myv * yl[1];
      yv[m][2] = myv * yl[2]; yv[m][3] = myv * yl[3];
    }

#pragma unroll
    for (int jc = 0; jc < 4; ++jc) {
      const int jj = jc * 64 + w * 16 + l15;
      const float wpr = WpT[p * NG + jj];
      const float wpz = WpT[p * NG + NH + jj];
      const float wpn = WpT[p * NG + 2 * NH + jj];

      f32x4 ar[2], az[2], an3[2], gin[2];
#pragma unroll
      for (int m = 0; m < 2; ++m) {
        const int r0g = row0 + m * 16 + lg * 4;
        f32x4 gr = *reinterpret_cast<const f32x4*>(&gxT[jj * NB + r0g]);
        f32x4 gz = *reinterpret_cast<const f32x4*>(&gxT[(NH + jj) * NB + r0g]);
        f32x4 gn = *reinterpret_cast<const f32x4*>(&gxT[(2 * NH + jj) * NB + r0g]);
#pragma unroll
        for (int q = 0; q < 4; ++q) {
          ar[m][q] = gr[q] + yv[m][q] * wpr + bhr[jc];
          az[m][q] = gz[q] + yv[m][q] * wpz + bhz[jc];
          gin[m][q] = gn[q] + yv[m][q] * wpn;
          an3[m][q] = bhn[jc];
        }
      }

      if (t > 0) {
        const int cc = jc * 4 + w;
#pragma unroll
        for (int kk = 0; kk < 8; ++kk) {
          const int k0 = kk * 32 + lg * 8;
          bf16x8 a[2];
#pragma unroll
          for (int m = 0; m < 2; ++m) {
            const int row = m * 16 + l15;
            a[m] = *reinterpret_cast<const bf16x8*>(&hr[row * NH + (k0 ^ ((row & 7) << 3))]);
          }
          const int boff = (cc << 12) + (kk << 9) + lane * 8;
          const bf16x8 br = *reinterpret_cast<const bf16x8*>(&Wp8[boff]);
          const bf16x8 bz = *reinterpret_cast<const bf16x8*>(&Wp8[65536 + boff]);
          const bf16x8 bn = *reinterpret_cast<const bf16x8*>(&Wp8[131072 + boff]);
#pragma unroll
          for (int m = 0; m < 2; ++m) {
            ar[m] = __builtin_amdgcn_mfma_f32_16x16x32_bf16(a[m], br, ar[m], 0, 0, 0);
            az[m] = __builtin_amdgcn_mfma_f32_16x16x32_bf16(a[m], bz, az[m], 0, 0, 0);
            an3[m] = __builtin_amdgcn_mfma_f32_16x16x32_bf16(a[m], bn, an3[m], 0, 0, 0);
          }
        }
      }

      // epilogue: pure register math; C/D layout col=lane&15, row=(lane>>4)*4+reg
#pragma unroll
      for (int m = 0; m < 2; ++m) {
#pragma unroll
        for (int i = 0; i < 2; ++i) {
          unsigned pack = 0;
#pragma unroll
          for (int hq = 0; hq < 2; ++hq) {
            const int q = i * 2 + hq;
            float r = fastsig(ar[m][q]);
            float z = fastsig(az[m][q]);
            float n = fasttanh(gin[m][q] + r * an3[m][q]);
            float hold = 0.0f;
            if (t > 0) {
              const unsigned hp = hreg[jc][m][i];
              hold = b2f((unsigned short)(hq ? (hp >> 16) : (hp & 0xffffu)));
            }
            float hnew = n + z * (hold - n);
            pack |= ((unsigned)f2b(hnew)) << (hq * 16);
          }
          hreg[jc][m][i] = pack;
          const int r0 = m * 16 + lg * 4 + i * 2;
          hw[r0 * NH + (jj ^ ((r0 & 7) << 3))] = (unsigned short)(pack & 0xffffu);
          hw[(r0 + 1) * NH + (jj ^ (((r0 + 1) & 7) << 3))] = (unsigned short)(pack >> 16);
        }
      }
    }
  }

  // ---- logits: out[b][c] = h . W_out[c] + b_out[c] ----
  __syncthreads();
  const unsigned short* hf = hb[nsteps & 1];
  {
    const int row = tid >> 3, part = tid & 7;  // 8 threads per batch row
    float s = 0.0f;
#pragma unroll
    for (int v = 0; v < 4; ++v) {
      const int e0 = part * 32 + v * 8;
      const bf16x8 hv = *reinterpret_cast<const bf16x8*>(&hf[row * NH + (e0 ^ ((row & 7) << 3))]);
      const f32x4 w0 = *reinterpret_cast<const f32x4*>(&W_out[c * NH + e0]);
      const f32x4 w1 = *reinterpret_cast<const f32x4*>(&W_out[c * NH + e0 + 4]);
      s += b2f((unsigned short)hv[0]) * w0[0] + b2f((unsigned short)hv[1]) * w0[1]
         + b2f((unsigned short)hv[2]) * w0[2] + b2f((unsigned short)hv[3]) * w0[3]
         + b2f((unsigned short)hv[4]) * w1[0] + b2f((unsigned short)hv[5]) * w1[1]
         + b2f((unsigned short)hv[6]) * w1[2] + b2f((unsigned short)hv[7]) * w1[3];
    }
    s += __shfl_xor(s, 1);
    s += __shfl_xor(s, 2);
    s += __shfl_xor(s, 4);
    if (part == 0) out[(row0 + row) * NC + c] = s + b_out[c];
  }
}

extern "C" void kernel_launch(void* const* d_in, const int* in_sizes, int n_in,
                              void* d_out, int out_size, void* d_ws, size_t ws_size,
                              hipStream_t stream)
{
  const float* X     = (const float*)d_in[0];
  const float* Y     = (const float*)d_in[1];
  const float* W_ih  = (const float*)d_in[2];
  const float* W_hh  = (const float*)d_in[3];
  const float* b_ih  = (const float*)d_in[4];
  const float* b_hh  = (const float*)d_in[5];
  const float* W_out = (const float*)d_in[6];
  const float* b_out = (const float*)d_in[7];
  float* out = (float*)d_out;

  char* ws = (char*)d_ws;
  float*          gxT = (float*)ws;                          // 6291456 B
  unsigned short* Xb  = (unsigned short*)(ws + 6291456);     // 2097152 B
  unsigned short* Wxb = (unsigned short*)(ws + 8388608);     //  786432 B
  unsigned short* Wp8 = (unsigned short*)(ws + 9175040);     //  393216 B
  float*          WpT = (float*)(ws + 9568256);              //  196608 B
  float*          YT  = (float*)(ws + 9764864);              //  524288 B

  k_prep<<<dim3(1024), dim3(256), 0, stream>>>(X, Y, W_ih, W_hh, Xb, Wxb, Wp8, WpT, YT);
  k_gx<<<dim3(32, 12), dim3(256), 0, stream>>>(Xb, Wxb, b_ih, gxT);
  k_chain<<<dim3(64, 64), dim3(256), 0, stream>>>(YT, gxT, Wp8, WpT, b_hh, W_out, b_out, out);
}

// Round 14
// 316.187 us; speedup vs baseline: 4.2724x; 1.5000x over previous
//
#include <hip/hip_runtime.h>

typedef __attribute__((ext_vector_type(8))) short bf16x8;
typedef __attribute__((ext_vector_type(4))) float f32x4;

#define NB 2048
#define NC 64
#define NH 256
#define ND 512
#define NG 768   // 3*NH
#define WIH_LD 576  // NC + ND

__device__ __forceinline__ unsigned short f2b(float f) {
  union { float f; unsigned u; } v; v.f = f;
  unsigned r = v.u + 0x7FFFu + ((v.u >> 16) & 1u);
  return (unsigned short)(r >> 16);
}
__device__ __forceinline__ float b2f(unsigned short h) {
  union { unsigned u; float f; } v; v.u = ((unsigned)h) << 16;
  return v.f;
}
__device__ __forceinline__ float fastsig(float x) {
  return __builtin_amdgcn_rcpf(1.0f + __expf(-x));
}
__device__ __forceinline__ float fasttanh(float x) {
  return 1.0f - 2.0f * __builtin_amdgcn_rcpf(__expf(2.0f * x) + 1.0f);
}

// ---------------- prep: bf16 conversions, packed W_hh, Y transpose ----------------
__global__ void k_prep(const float* __restrict__ X, const float* __restrict__ Y,
                       const float* __restrict__ W_ih, const float* __restrict__ W_hh,
                       unsigned short* __restrict__ Xb, unsigned short* __restrict__ Wxb,
                       unsigned short* __restrict__ Wp8, float* __restrict__ WpT,
                       float* __restrict__ YT)
{
  const int stride = gridDim.x * blockDim.x;
  const int i0 = blockIdx.x * blockDim.x + threadIdx.x;
  for (int i = i0; i < NB * ND; i += stride) Xb[i] = f2b(X[i]);
  for (int i = i0; i < NG * ND; i += stride) {
    int r = i >> 9, k = i & (ND - 1);
    Wxb[i] = f2b(W_ih[r * WIH_LD + NC + k]);
  }
  // W_hh packed to MFMA fragment order: i = (g<<16)+(cc<<12)+(kk<<9)+(lane<<3)+e
  for (int i = i0; i < NG * NH; i += stride) {
    int e = i & 7, ln = (i >> 3) & 63, kk = (i >> 9) & 7, cc = (i >> 12) & 15, g = i >> 16;
    int col = cc * 16 + (ln & 15), k = kk * 32 + (ln >> 4) * 8 + e;
    Wp8[i] = f2b(W_hh[(g * NH + col) * NH + k]);
  }
  for (int i = i0; i < NC * NG; i += stride) {
    int p = i / NG, g = i - p * NG;
    WpT[i] = W_ih[g * WIH_LD + p];
  }
  // Y transposed: YT[p][b] = Y[b][p]   (524288 B, fully initialized)
  for (int i = i0; i < NC * NB; i += stride) {
    int cbl = i >> 11, b = i & (NB - 1);
    YT[i] = Y[b * NC + cbl];
  }
}

// ---------------- gxP = fragment-packed (Xb @ Wxb^T + b_ih + b_hh[r,z]) ----------------
// gxP[((c16*128 + rt)*64 + lane)*4 + q]; c16 = global col/16 (0..47), rt = row/16
__global__ __launch_bounds__(256) void k_gx(const unsigned short* __restrict__ Xb,
                                            const unsigned short* __restrict__ Wxb,
                                            const float* __restrict__ b_ih,
                                            const float* __restrict__ b_hh,
                                            float* __restrict__ gxP)
{
  const int row0 = blockIdx.x * 64;
  const int col0 = blockIdx.y * 64;
  const int tid = threadIdx.x;
  const int w = tid >> 6, lane = tid & 63;
  const int l15 = lane & 15, lg = lane >> 4;
  const int col = col0 + w * 16 + l15;
  f32x4 acc[4] = {};
  for (int kk = 0; kk < 16; ++kk) {
    const int k0 = kk * 32 + lg * 8;
    bf16x8 b = *reinterpret_cast<const bf16x8*>(&Wxb[col * ND + k0]);
#pragma unroll
    for (int m = 0; m < 4; ++m) {
      const int row = row0 + m * 16 + l15;
      bf16x8 a = *reinterpret_cast<const bf16x8*>(&Xb[row * ND + k0]);
      acc[m] = __builtin_amdgcn_mfma_f32_16x16x32_bf16(a, b, acc[m], 0, 0, 0);
    }
  }
  float bi = b_ih[col];
  if (col < 2 * NH) bi += b_hh[col];   // fold r,z hidden bias; n-gate bias stays separate
  const int c16 = col0 / 16 + w;
#pragma unroll
  for (int m = 0; m < 4; ++m) {
    f32x4 o = acc[m];
    o[0] += bi; o[1] += bi; o[2] += bi; o[3] += bi;
    const int rt = row0 / 16 + m;
    *reinterpret_cast<f32x4*>(&gxP[((c16 * 128 + rt) * 64 + lane) * 4]) = o;
  }
}

// ---------------- fused GRU chain + logits ----------------
// grid: (64 batch-tiles of 32 rows, 64 classes), 512 threads (8 waves)
// wave w owns col-chunks cc = {2w, 2w+1}; LDS: 32 KB h double-buffer (XOR-swizzled)
__global__ __launch_bounds__(512) void k_chain(const float* __restrict__ YT,
                                               const float* __restrict__ gxP,
                                               const unsigned short* __restrict__ Wp8,
                                               const float* __restrict__ WpT,
                                               const float* __restrict__ b_hh,
                                               const float* __restrict__ W_out,
                                               const float* __restrict__ b_out,
                                               float* __restrict__ out)
{
  __shared__ unsigned short hb[2][32 * NH];   // 2 x 16384 B

  const int c = blockIdx.y;
  const int rt0 = blockIdx.x * 2;             // row-tile base (16-row tiles)
  const int row0 = blockIdx.x * 32;
  const int tid = threadIdx.x;
  const int w = tid >> 6, lane = tid & 63;
  const int l15 = lane & 15, lg = lane >> 4;
  const int nsteps = (c == 0) ? 1 : (c < 3 ? c : 3);
  const float myv = (c == 0) ? 0.0f : 1.0f;
  const int pbase = (c == 0) ? 0 : (c - nsteps);

  // n-gate hidden bias per jc (constant across steps)
  float bhn[2];
#pragma unroll
  for (int jc = 0; jc < 2; ++jc) bhn[jc] = b_hh[2 * NH + (w * 2 + jc) * 16 + l15];

  unsigned hreg[2][2][2];   // packed bf16 pairs: [jc][m][qpair]

  for (int t = 0; t < nsteps; ++t) {
    const int p = pbase + t;
    const unsigned short* hr = hb[t & 1];
    unsigned short* hw = hb[(t + 1) & 1];
    if (t > 0) __syncthreads();   // prev step's writes visible before A-frag reads

    // yv per 4-row group (quarter-wave broadcast loads, L1-served)
    f32x4 yv[2];
#pragma unroll
    for (int m = 0; m < 2; ++m) {
      f32x4 yl = *reinterpret_cast<const f32x4*>(&YT[p * NB + row0 + m * 16 + lg * 4]);
      yv[m][0] = myv * yl[0]; yv[m][1] = myv * yl[1];
      yv[m][2] = myv * yl[2]; yv[m][3] = myv * yl[3];
    }

#pragma unroll
    for (int jc = 0; jc < 2; ++jc) {
      const int cc = w * 2 + jc;
      const int jj = cc * 16 + l15;
      const float wpr = WpT[p * NG + jj];
      const float wpz = WpT[p * NG + NH + jj];
      const float wpn = WpT[p * NG + 2 * NH + jj];

      f32x4 ar[2], az[2], an3[2], gin[2];
#pragma unroll
      for (int m = 0; m < 2; ++m) {
        const int rt = rt0 + m;
        f32x4 gr = *reinterpret_cast<const f32x4*>(&gxP[((cc * 128 + rt) * 64 + lane) * 4]);
        f32x4 gz = *reinterpret_cast<const f32x4*>(&gxP[(((16 + cc) * 128 + rt) * 64 + lane) * 4]);
        f32x4 gn = *reinterpret_cast<const f32x4*>(&gxP[(((32 + cc) * 128 + rt) * 64 + lane) * 4]);
#pragma unroll
        for (int q = 0; q < 4; ++q) {
          ar[m][q] = gr[q] + yv[m][q] * wpr;
          az[m][q] = gz[q] + yv[m][q] * wpz;
          gin[m][q] = gn[q] + yv[m][q] * wpn;
          an3[m][q] = bhn[jc];
        }
      }

      if (t > 0) {
#pragma unroll 2
        for (int kk = 0; kk < 8; ++kk) {
          const int k0 = kk * 32 + lg * 8;
          bf16x8 a[2];
#pragma unroll
          for (int m = 0; m < 2; ++m) {
            const int row = m * 16 + l15;
            a[m] = *reinterpret_cast<const bf16x8*>(&hr[row * NH + (k0 ^ ((row & 7) << 3))]);
          }
          const int boff = (cc << 12) + (kk << 9) + lane * 8;
          const bf16x8 br = *reinterpret_cast<const bf16x8*>(&Wp8[boff]);
          const bf16x8 bz = *reinterpret_cast<const bf16x8*>(&Wp8[65536 + boff]);
          const bf16x8 bn = *reinterpret_cast<const bf16x8*>(&Wp8[131072 + boff]);
#pragma unroll
          for (int m = 0; m < 2; ++m) {
            ar[m] = __builtin_amdgcn_mfma_f32_16x16x32_bf16(a[m], br, ar[m], 0, 0, 0);
            az[m] = __builtin_amdgcn_mfma_f32_16x16x32_bf16(a[m], bz, az[m], 0, 0, 0);
            an3[m] = __builtin_amdgcn_mfma_f32_16x16x32_bf16(a[m], bn, an3[m], 0, 0, 0);
          }
        }
      }

      // epilogue: pure register math; C/D layout col=lane&15, row=(lane>>4)*4+reg
#pragma unroll
      for (int m = 0; m < 2; ++m) {
#pragma unroll
        for (int i = 0; i < 2; ++i) {
          unsigned pack = 0;
#pragma unroll
          for (int hq = 0; hq < 2; ++hq) {
            const int q = i * 2 + hq;
            float r = fastsig(ar[m][q]);
            float z = fastsig(az[m][q]);
            float n = fasttanh(gin[m][q] + r * an3[m][q]);
            float hold = 0.0f;
            if (t > 0) {
              const unsigned hp = hreg[jc][m][i];
              hold = b2f((unsigned short)(hq ? (hp >> 16) : (hp & 0xffffu)));
            }
            float hnew = n + z * (hold - n);
            pack |= ((unsigned)f2b(hnew)) << (hq * 16);
          }
          hreg[jc][m][i] = pack;
          const int r0 = m * 16 + lg * 4 + i * 2;
          hw[r0 * NH + (jj ^ ((r0 & 7) << 3))] = (unsigned short)(pack & 0xffffu);
          hw[(r0 + 1) * NH + (jj ^ (((r0 + 1) & 7) << 3))] = (unsigned short)(pack >> 16);
        }
      }
    }
  }

  // ---- logits: out[b][c] = h . W_out[c] + b_out[c] ----
  __syncthreads();
  const unsigned short* hf = hb[nsteps & 1];
  {
    const int row = tid >> 4, part = tid & 15;  // 16 threads per batch row
    float s = 0.0f;
#pragma unroll
    for (int v = 0; v < 2; ++v) {
      const int e0 = part * 16 + v * 8;
      const bf16x8 hv = *reinterpret_cast<const bf16x8*>(&hf[row * NH + (e0 ^ ((row & 7) << 3))]);
      const f32x4 w0 = *reinterpret_cast<const f32x4*>(&W_out[c * NH + e0]);
      const f32x4 w1 = *reinterpret_cast<const f32x4*>(&W_out[c * NH + e0 + 4]);
      s += b2f((unsigned short)hv[0]) * w0[0] + b2f((unsigned short)hv[1]) * w0[1]
         + b2f((unsigned short)hv[2]) * w0[2] + b2f((unsigned short)hv[3]) * w0[3]
         + b2f((unsigned short)hv[4]) * w1[0] + b2f((unsigned short)hv[5]) * w1[1]
         + b2f((unsigned short)hv[6]) * w1[2] + b2f((unsigned short)hv[7]) * w1[3];
    }
    s += __shfl_xor(s, 1);
    s += __shfl_xor(s, 2);
    s += __shfl_xor(s, 4);
    s += __shfl_xor(s, 8);
    if (part == 0) out[(row0 + row) * NC + c] = s + b_out[c];
  }
}

extern "C" void kernel_launch(void* const* d_in, const int* in_sizes, int n_in,
                              void* d_out, int out_size, void* d_ws, size_t ws_size,
                              hipStream_t stream)
{
  const float* X     = (const float*)d_in[0];
  const float* Y     = (const float*)d_in[1];
  const float* W_ih  = (const float*)d_in[2];
  const float* W_hh  = (const float*)d_in[3];
  const float* b_ih  = (const float*)d_in[4];
  const float* b_hh  = (const float*)d_in[5];
  const float* W_out = (const float*)d_in[6];
  const float* b_out = (const float*)d_in[7];
  float* out = (float*)d_out;

  char* ws = (char*)d_ws;
  float*          gxP = (float*)ws;                          // 6291456 B
  unsigned short* Xb  = (unsigned short*)(ws + 6291456);     // 2097152 B
  unsigned short* Wxb = (unsigned short*)(ws + 8388608);     //  786432 B
  unsigned short* Wp8 = (unsigned short*)(ws + 9175040);     //  393216 B
  float*          WpT = (float*)(ws + 9568256);              //  196608 B
  float*          YT  = (float*)(ws + 9764864);              //  524288 B

  k_prep<<<dim3(1024), dim3(256), 0, stream>>>(X, Y, W_ih, W_hh, Xb, Wxb, Wp8, WpT, YT);
  k_gx<<<dim3(32, 12), dim3(256), 0, stream>>>(Xb, Wxb, b_ih, b_hh, gxP);
  k_chain<<<dim3(64, 64), dim3(512), 0, stream>>>(YT, gxP, Wp8, WpT, b_hh, W_out, b_out, out);
}

// Round 15
// 315.014 us; speedup vs baseline: 4.2883x; 1.0037x over previous
//
#include <hip/hip_runtime.h>

typedef __attribute__((ext_vector_type(8))) short bf16x8;
typedef __attribute__((ext_vector_type(4))) float f32x4;

#define NB 2048
#define NC 64
#define NH 256
#define ND 512
#define NG 768   // 3*NH
#define WIH_LD 576  // NC + ND

__device__ __forceinline__ unsigned short f2b(float f) {
  union { float f; unsigned u; } v; v.f = f;
  unsigned r = v.u + 0x7FFFu + ((v.u >> 16) & 1u);
  return (unsigned short)(r >> 16);
}
__device__ __forceinline__ float b2f(unsigned short h) {
  union { unsigned u; float f; } v; v.u = ((unsigned)h) << 16;
  return v.f;
}
__device__ __forceinline__ float fastsig(float x) {
  return __builtin_amdgcn_rcpf(1.0f + __expf(-x));
}
__device__ __forceinline__ float fasttanh(float x) {
  return 1.0f - 2.0f * __builtin_amdgcn_rcpf(__expf(2.0f * x) + 1.0f);
}

// ---------------- prep: bf16 conversions, packed W_hh, Y transpose ----------------
__global__ void k_prep(const float* __restrict__ X, const float* __restrict__ Y,
                       const float* __restrict__ W_ih, const float* __restrict__ W_hh,
                       unsigned short* __restrict__ Xb, unsigned short* __restrict__ Wxb,
                       unsigned short* __restrict__ Wp8, float* __restrict__ WpT,
                       float* __restrict__ YT)
{
  const int stride = gridDim.x * blockDim.x;
  const int i0 = blockIdx.x * blockDim.x + threadIdx.x;
  for (int i = i0; i < NB * ND; i += stride) Xb[i] = f2b(X[i]);
  for (int i = i0; i < NG * ND; i += stride) {
    int r = i >> 9, k = i & (ND - 1);
    Wxb[i] = f2b(W_ih[r * WIH_LD + NC + k]);
  }
  // W_hh packed to MFMA fragment order: i = (g<<16)+(cc<<12)+(kk<<9)+(lane<<3)+e
  for (int i = i0; i < NG * NH; i += stride) {
    int e = i & 7, ln = (i >> 3) & 63, kk = (i >> 9) & 7, cc = (i >> 12) & 15, g = i >> 16;
    int col = cc * 16 + (ln & 15), k = kk * 32 + (ln >> 4) * 8 + e;
    Wp8[i] = f2b(W_hh[(g * NH + col) * NH + k]);
  }
  for (int i = i0; i < NC * NG; i += stride) {
    int p = i / NG, g = i - p * NG;
    WpT[i] = W_ih[g * WIH_LD + p];
  }
  // Y transposed: YT[p][b] = Y[b][p]
  for (int i = i0; i < NC * NB; i += stride) {
    int cbl = i >> 11, b = i & (NB - 1);
    YT[i] = Y[b * NC + cbl];
  }
}

// ---------------- gxP = fragment-packed (Xb @ Wxb^T + b_ih + b_hh[r,z]) ----------------
// gxP[((c16*128 + rt)*64 + lane)*4 + q]; c16 = global col/16 (0..47), rt = row/16
__global__ __launch_bounds__(256) void k_gx(const unsigned short* __restrict__ Xb,
                                            const unsigned short* __restrict__ Wxb,
                                            const float* __restrict__ b_ih,
                                            const float* __restrict__ b_hh,
                                            float* __restrict__ gxP)
{
  const int row0 = blockIdx.x * 64;
  const int col0 = blockIdx.y * 64;
  const int tid = threadIdx.x;
  const int w = tid >> 6, lane = tid & 63;
  const int l15 = lane & 15, lg = lane >> 4;
  const int col = col0 + w * 16 + l15;
  f32x4 acc[4] = {};
  for (int kk = 0; kk < 16; ++kk) {
    const int k0 = kk * 32 + lg * 8;
    bf16x8 b = *reinterpret_cast<const bf16x8*>(&Wxb[col * ND + k0]);
#pragma unroll
    for (int m = 0; m < 4; ++m) {
      const int row = row0 + m * 16 + l15;
      bf16x8 a = *reinterpret_cast<const bf16x8*>(&Xb[row * ND + k0]);
      acc[m] = __builtin_amdgcn_mfma_f32_16x16x32_bf16(a, b, acc[m], 0, 0, 0);
    }
  }
  float bi = b_ih[col];
  if (col < 2 * NH) bi += b_hh[col];   // fold r,z hidden bias; n-gate bias stays separate
  const int c16 = col0 / 16 + w;
#pragma unroll
  for (int m = 0; m < 4; ++m) {
    f32x4 o = acc[m];
    o[0] += bi; o[1] += bi; o[2] += bi; o[3] += bi;
    const int rt = row0 / 16 + m;
    *reinterpret_cast<f32x4*>(&gxP[((c16 * 128 + rt) * 64 + lane) * 4]) = o;
  }
}

// ---------------- fused GRU chain + logits ----------------
// grid: 4096 linear blocks, XCD-pinned: XCD k = wgid&7 owns tiles 8k..8k+7 for ALL
// classes -> per-XCD L2 working set = 8x96KB gx + 393KB W (~1.2MB << 4MB L2).
// 512 threads (8 waves); wave w owns col-chunks cc = {2w, 2w+1}; 32KB LDS h dbuf.
__global__ __launch_bounds__(512) void k_chain(const float* __restrict__ YT,
                                               const float* __restrict__ gxP,
                                               const unsigned short* __restrict__ Wp8,
                                               const float* __restrict__ WpT,
                                               const float* __restrict__ b_hh,
                                               const float* __restrict__ W_out,
                                               const float* __restrict__ b_out,
                                               float* __restrict__ out)
{
  __shared__ unsigned short hb[2][32 * NH];   // 2 x 16384 B

  // XCD tile-pinning swizzle (bijective: 4096 = 8 xcd * 8 tile * 64 class)
  const int wgid = blockIdx.x;
  const int xcd = wgid & 7;
  const int j = wgid >> 3;
  const int tile = xcd * 8 + (j & 7);
  const int c = j >> 3;

  const int rt0 = tile * 2;             // row-tile base (16-row tiles)
  const int row0 = tile * 32;
  const int tid = threadIdx.x;
  const int w = tid >> 6, lane = tid & 63;
  const int l15 = lane & 15, lg = lane >> 4;
  const int nsteps = (c == 0) ? 1 : (c < 3 ? c : 3);
  const float myv = (c == 0) ? 0.0f : 1.0f;
  const int pbase = (c == 0) ? 0 : (c - nsteps);

  // n-gate hidden bias per jc (constant across steps)
  float bhn[2];
#pragma unroll
  for (int jc = 0; jc < 2; ++jc) bhn[jc] = b_hh[2 * NH + (w * 2 + jc) * 16 + l15];

  unsigned hreg[2][2][2];   // packed bf16 pairs: [jc][m][qpair]

  for (int t = 0; t < nsteps; ++t) {
    const int p = pbase + t;
    const unsigned short* hr = hb[t & 1];
    unsigned short* hw = hb[(t + 1) & 1];
    if (t > 0) __syncthreads();   // prev step's writes visible before A-frag reads

    // yv per 4-row group (quarter-wave broadcast loads, L1-served)
    f32x4 yv[2];
#pragma unroll
    for (int m = 0; m < 2; ++m) {
      f32x4 yl = *reinterpret_cast<const f32x4*>(&YT[p * NB + row0 + m * 16 + lg * 4]);
      yv[m][0] = myv * yl[0]; yv[m][1] = myv * yl[1];
      yv[m][2] = myv * yl[2]; yv[m][3] = myv * yl[3];
    }

#pragma unroll
    for (int jc = 0; jc < 2; ++jc) {
      const int cc = w * 2 + jc;
      const int jj = cc * 16 + l15;
      const float wpr = WpT[p * NG + jj];
      const float wpz = WpT[p * NG + NH + jj];
      const float wpn = WpT[p * NG + 2 * NH + jj];

      f32x4 ar[2], az[2], an3[2], gin[2];
#pragma unroll
      for (int m = 0; m < 2; ++m) {
        const int rt = rt0 + m;
        f32x4 gr = *reinterpret_cast<const f32x4*>(&gxP[((cc * 128 + rt) * 64 + lane) * 4]);
        f32x4 gz = *reinterpret_cast<const f32x4*>(&gxP[(((16 + cc) * 128 + rt) * 64 + lane) * 4]);
        f32x4 gn = *reinterpret_cast<const f32x4*>(&gxP[(((32 + cc) * 128 + rt) * 64 + lane) * 4]);
#pragma unroll
        for (int q = 0; q < 4; ++q) {
          ar[m][q] = gr[q] + yv[m][q] * wpr;
          az[m][q] = gz[q] + yv[m][q] * wpz;
          gin[m][q] = gn[q] + yv[m][q] * wpn;
          an3[m][q] = bhn[jc];
        }
      }

      if (t > 0) {
#pragma unroll 2
        for (int kk = 0; kk < 8; ++kk) {
          const int k0 = kk * 32 + lg * 8;
          bf16x8 a[2];
#pragma unroll
          for (int m = 0; m < 2; ++m) {
            const int row = m * 16 + l15;
            a[m] = *reinterpret_cast<const bf16x8*>(&hr[row * NH + (k0 ^ ((row & 7) << 3))]);
          }
          const int boff = (cc << 12) + (kk << 9) + lane * 8;
          const bf16x8 br = *reinterpret_cast<const bf16x8*>(&Wp8[boff]);
          const bf16x8 bz = *reinterpret_cast<const bf16x8*>(&Wp8[65536 + boff]);
          const bf16x8 bn = *reinterpret_cast<const bf16x8*>(&Wp8[131072 + boff]);
#pragma unroll
          for (int m = 0; m < 2; ++m) {
            ar[m] = __builtin_amdgcn_mfma_f32_16x16x32_bf16(a[m], br, ar[m], 0, 0, 0);
            az[m] = __builtin_amdgcn_mfma_f32_16x16x32_bf16(a[m], bz, az[m], 0, 0, 0);
            an3[m] = __builtin_amdgcn_mfma_f32_16x16x32_bf16(a[m], bn, an3[m], 0, 0, 0);
          }
        }
      }

      // epilogue: pure register math; C/D layout col=lane&15, row=(lane>>4)*4+reg
#pragma unroll
      for (int m = 0; m < 2; ++m) {
#pragma unroll
        for (int i = 0; i < 2; ++i) {
          unsigned pack = 0;
#pragma unroll
          for (int hq = 0; hq < 2; ++hq) {
            const int q = i * 2 + hq;
            float r = fastsig(ar[m][q]);
            float z = fastsig(az[m][q]);
            float n = fasttanh(gin[m][q] + r * an3[m][q]);
            float hold = 0.0f;
            if (t > 0) {
              const unsigned hp = hreg[jc][m][i];
              hold = b2f((unsigned short)(hq ? (hp >> 16) : (hp & 0xffffu)));
            }
            float hnew = n + z * (hold - n);
            pack |= ((unsigned)f2b(hnew)) << (hq * 16);
          }
          hreg[jc][m][i] = pack;
          const int r0 = m * 16 + lg * 4 + i * 2;
          hw[r0 * NH + (jj ^ ((r0 & 7) << 3))] = (unsigned short)(pack & 0xffffu);
          hw[(r0 + 1) * NH + (jj ^ (((r0 + 1) & 7) << 3))] = (unsigned short)(pack >> 16);
        }
      }
    }
  }

  // ---- logits: out[b][c] = h . W_out[c] + b_out[c] ----
  __syncthreads();
  const unsigned short* hf = hb[nsteps & 1];
  {
    const int row = tid >> 4, part = tid & 15;  // 16 threads per batch row
    float s = 0.0f;
#pragma unroll
    for (int v = 0; v < 2; ++v) {
      const int e0 = part * 16 + v * 8;
      const bf16x8 hv = *reinterpret_cast<const bf16x8*>(&hf[row * NH + (e0 ^ ((row & 7) << 3))]);
      const f32x4 w0 = *reinterpret_cast<const f32x4*>(&W_out[c * NH + e0]);
      const f32x4 w1 = *reinterpret_cast<const f32x4*>(&W_out[c * NH + e0 + 4]);
      s += b2f((unsigned short)hv[0]) * w0[0] + b2f((unsigned short)hv[1]) * w0[1]
         + b2f((unsigned short)hv[2]) * w0[2] + b2f((unsigned short)hv[3]) * w0[3]
         + b2f((unsigned short)hv[4]) * w1[0] + b2f((unsigned short)hv[5]) * w1[1]
         + b2f((unsigned short)hv[6]) * w1[2] + b2f((unsigned short)hv[7]) * w1[3];
    }
    s += __shfl_xor(s, 1);
    s += __shfl_xor(s, 2);
    s += __shfl_xor(s, 4);
    s += __shfl_xor(s, 8);
    if (part == 0) out[(row0 + row) * NC + c] = s + b_out[c];
  }
}

extern "C" void kernel_launch(void* const* d_in, const int* in_sizes, int n_in,
                              void* d_out, int out_size, void* d_ws, size_t ws_size,
                              hipStream_t stream)
{
  const float* X     = (const float*)d_in[0];
  const float* Y     = (const float*)d_in[1];
  const float* W_ih  = (const float*)d_in[2];
  const float* W_hh  = (const float*)d_in[3];
  const float* b_ih  = (const float*)d_in[4];
  const float* b_hh  = (const float*)d_in[5];
  const float* W_out = (const float*)d_in[6];
  const float* b_out = (const float*)d_in[7];
  float* out = (float*)d_out;

  char* ws = (char*)d_ws;
  float*          gxP = (float*)ws;                          // 6291456 B
  unsigned short* Xb  = (unsigned short*)(ws + 6291456);     // 2097152 B
  unsigned short* Wxb = (unsigned short*)(ws + 8388608);     //  786432 B
  unsigned short* Wp8 = (unsigned short*)(ws + 9175040);     //  393216 B
  float*          WpT = (float*)(ws + 9568256);              //  196608 B
  float*          YT  = (float*)(ws + 9764864);              //  524288 B

  k_prep<<<dim3(1024), dim3(256), 0, stream>>>(X, Y, W_ih, W_hh, Xb, Wxb, Wp8, WpT, YT);
  k_gx<<<dim3(32, 12), dim3(256), 0, stream>>>(Xb, Wxb, b_ih, b_hh, gxP);
  k_chain<<<dim3(4096), dim3(512), 0, stream>>>(YT, gxP, Wp8, WpT, b_hh, W_out, b_out, out);
}